// Round 2
// baseline (205.729 us; speedup 1.0000x reference)
//
#include <hip/hip_runtime.h>
#include <stdint.h>

// Dyna_Dec: out[b,d,l] = sum_c x[b,c,l] * w[l,c,d] + bias[l,d]
// B=128, C=32, L=4096. fp32 in/out.
//
// R6 (88us): W loads lane-scattered (4KB stride) -> L1 tag-lookup bound.
// R7 (104us): LDS-staged W fixed the scatter (conflicts 0, occ 37%) BUT
//   acc[8][8]+temps > the 64-VGPR budget the compiler picked -> scratch
//   spill: WRITE_SIZE 64->102MB, FETCH +10MB. Spill ate the win.
//
// R8: same LDS staging, half the per-thread state. kNB 8->4 (acc[4][8]=32
// regs, ~60 VGPR total -> no spill), gridDim.y 16->32 (2048 blocks, more
// TLP). Per c-chunk of 4, the block's W slice (64 l x 4 c x 32 d = 32 KB)
// is loaded with fully-coalesced float4 reads (contiguous 512 B per l-row)
// and written to LDS with a 16B-slot XOR swizzle (slot ^ (l&31)) so both
// ds_write_b128 (staging) and ds_read_b128 (compute: same-offset-
// different-row) are conflict-free. 32 KB LDS -> 5 blocks/CU -> 20
// waves/CU. blockIdx linearization keeps all 32 b-blocks of one l-chunk on
// one XCD (id%8 == blockIdx.x%8) -> W slice L2-resident.

namespace {

constexpr int kC  = 32;
constexpr int kL  = 4096;
constexpr int kNB = 4;   // batches per thread
constexpr int kND = 8;   // d-channels per thread
constexpr int kCC = 4;   // c-chunk staged in LDS per round
constexpr int kLB = 64;  // l-positions per block
constexpr int kRowF = kCC * kC;            // 128 floats per LDS l-row
constexpr int kChunkFloats = kLB * kRowF;  // 8192 floats = 32 KB

__global__ __launch_bounds__(256, 4)
void dyna_dec(const float* __restrict__ x,
              const float* __restrict__ w,
              const float* __restrict__ bias,
              float* __restrict__ out) {
    __shared__ __align__(16) float lds[kChunkFloats];

    const int tid = threadIdx.x;
    const int lt  = tid & 63;          // lane = l within chunk (coalescing dim)
    const int dg  = tid >> 6;          // wave = d-group 0..3
    const int l   = blockIdx.x * kLB + lt;      // gridDim.x = L/64 = 64
    const int b0  = blockIdx.y * kNB;           // gridDim.y = B/4  = 32
    const int d0  = dg * kND;

    const float* xp = x + (size_t)b0 * (kC * kL) + l;           // x[b0, 0, l]
    const float* wb = w + (size_t)blockIdx.x * kLB * (kC * kC); // block's W rows

    float acc[kNB][kND];
#pragma unroll
    for (int i = 0; i < kNB; ++i)
#pragma unroll
        for (int j = 0; j < kND; ++j) acc[i][j] = 0.0f;

    for (int cb = 0; cb < kC; cb += kCC) {
        __syncthreads();  // previous chunk's LDS reads complete

        // Stage W[l0..l0+63, cb..cb+kCC-1, 0..31] -> LDS.
        // 16B slots: s = tid + k*256 in [0,2048); row ls = s>>5, slot cs = s&31.
        // Global: per-row contiguous 512 B (coalesced). LDS: slot XOR (ls&31).
#pragma unroll
        for (int k = 0; k < 8; ++k) {
            const int s  = tid + k * 256;
            const int ls = s >> 5;
            const int cs = s & 31;
            const float4 v = *reinterpret_cast<const float4*>(
                wb + (size_t)ls * (kC * kC) + cb * kC + cs * 4);
            *reinterpret_cast<float4*>(
                &lds[ls * kRowF + ((cs ^ (ls & 31)) << 2)]) = v;
        }
        __syncthreads();  // chunk visible to all waves

#pragma unroll
        for (int c = 0; c < kCC; ++c) {
            // W[l, cb+c, d0..d0+7] = two swizzled 16B slots of row lt
            const int s16 = c * 8 + (d0 >> 2);
            const float4 w0 = *reinterpret_cast<const float4*>(
                &lds[lt * kRowF + (((s16 + 0) ^ (lt & 31)) << 2)]);
            const float4 w1 = *reinterpret_cast<const float4*>(
                &lds[lt * kRowF + (((s16 + 1) ^ (lt & 31)) << 2)]);
            const float ws[kND] = {w0.x, w0.y, w0.z, w0.w,
                                   w1.x, w1.y, w1.z, w1.w};

            // x[b0+i, cb+c, l]: coalesced over lanes, 4 independent loads
            float xr[kNB];
#pragma unroll
            for (int i = 0; i < kNB; ++i)
                xr[i] = xp[(size_t)i * (kC * kL) + (size_t)(cb + c) * kL];

#pragma unroll
            for (int i = 0; i < kNB; ++i)
#pragma unroll
                for (int j = 0; j < kND; ++j)
                    acc[i][j] += xr[i] * ws[j];
        }
    }

    // bias[l, d0..d0+7]
    const float4 b0v = *reinterpret_cast<const float4*>(bias + (size_t)l * kC + d0);
    const float4 b1v = *reinterpret_cast<const float4*>(bias + (size_t)l * kC + d0 + 4);
    const float bv[kND] = {b0v.x, b0v.y, b0v.z, b0v.w, b1v.x, b1v.y, b1v.z, b1v.w};

#pragma unroll
    for (int i = 0; i < kNB; ++i) {
        float* op = out + (size_t)(b0 + i) * (kC * kL) + l;
#pragma unroll
        for (int j = 0; j < kND; ++j)
            op[(size_t)(d0 + j) * kL] = acc[i][j] + bv[j];  // coalesced over l
    }
}

}  // namespace

extern "C" void kernel_launch(void* const* d_in, const int* in_sizes, int n_in,
                              void* d_out, int out_size, void* d_ws, size_t ws_size,
                              hipStream_t stream) {
    // inputs: 0=x (B,C,H,W) fp32, 1=px (unused), 2=weight (L*C, C) fp32,
    //         3=bias (L*C) fp32
    const float* x    = (const float*)d_in[0];
    const float* wgt  = (const float*)d_in[2];
    const float* bias = (const float*)d_in[3];
    float* out = (float*)d_out;

    dim3 grid(kL / 64, 128 / kNB);  // 64 x 32 = 2048 blocks
    dim3 block(256);
    hipLaunchKernelGGL(dyna_dec, grid, block, 0, stream, x, wgt, bias, out);
}

// Round 3
// 166.139 us; speedup vs baseline: 1.2383x; 1.2383x over previous
//
#include <hip/hip_runtime.h>
#include <stdint.h>

// Dyna_Dec: out[b,d,l] = sum_c x[b,c,l] * w[l,c,d] + bias[l,d]
// B=128, C=32, L=4096. fp32 in/out.
//
// R6 (88us/disp): W loads lane-scattered (4KB stride, 64 lines/wave-load)
//   -> L1 serialization; no barriers though, so loads pipelined.
// R7 (104us): LDS staging fixed scatter but acc[8][8] spilled (WRITE +39MB).
// R8 (115us): spill fixed (WRITE exactly 64MB, VGPR 52) but still slow:
//   each chunk is a serial convoy {barrier, glb loads, ds_write, barrier,
//   compute} -- zero overlap, stage latency fully exposed. VALUBusy 12%.
//
// R9: restore pipelining while keeping the scatter fix.
//  - Double-buffered W chunks (CC=2 c's: 16KB x2 = 32KB LDS, 5 blocks/CU).
//    Per iter: stage(next chunk) async, prefetch x(next) to regs, compute
//    (cur) from LDS+regs, one __syncthreads.
//  - Staging via __builtin_amdgcn_global_load_lds width=16: no VGPR round
//    trip, LDS written linearly (DMA: uniform base + lane*16). The XOR
//    bank-swizzle is applied by PRE-SWIZZLING the global source address
//    (linear dest + inverse-swz source + swz read = the correct pattern).
//  - Read side: slot s = l*16 + c*8 + dslot, read dslot = (2dg+j)^(l&7)
//    -> banks uniformly covered, conflict-free ds_read_b128.
//  - kNB=4 (spill-free). Grid (64,32); id%8==blockIdx.x%8 keeps one
//    l-chunk's W slice on one XCD's L2.

namespace {

constexpr int kC  = 32;
constexpr int kL  = 4096;
constexpr int kNB = 4;   // batches per thread
constexpr int kND = 8;   // d-channels per thread
constexpr int kCC = 2;   // c's per staged chunk
constexpr int kLB = 64;  // l-positions per block
constexpr int kChunks = kC / kCC;                 // 16
constexpr int kChunkFloats = kLB * kCC * kC;      // 4096 floats = 16 KB

__device__ __forceinline__ void async_ld16(const float* g, float* l) {
    __builtin_amdgcn_global_load_lds(
        (__attribute__((address_space(1))) const void*)g,
        (__attribute__((address_space(3))) void*)l, 16, 0, 0);
}

__global__ __launch_bounds__(256, 4)
void dyna_dec(const float* __restrict__ x,
              const float* __restrict__ w,
              const float* __restrict__ bias,
              float* __restrict__ out) {
    __shared__ __align__(16) float ldsA[kChunkFloats];
    __shared__ __align__(16) float ldsB[kChunkFloats];

    const int tid = threadIdx.x;
    const int lt  = tid & 63;          // lane = l within chunk (coalescing dim)
    const int dg  = tid >> 6;          // wave = d-group 0..3
    const int l   = blockIdx.x * kLB + lt;      // gridDim.x = 64
    const int b0  = blockIdx.y * kNB;           // gridDim.y = 32
    const int d0  = dg * kND;

    const float* xp = x + (size_t)b0 * (kC * kL) + l;
    const float* wb = w + (size_t)blockIdx.x * kLB * (kC * kC);

    // Staging geometry: 1024 16B-slots per chunk. Wave dg, call k, lane lt
    // fills slot s = dg*256 + k*64 + lt  (DMA: uniform base + lane*16).
    // Slot s holds W[ls, cb*kCC+cs, 4*(dsl^(ls&7)) .. +4) where
    // ls = s>>4, cs = (s>>3)&1, dsl = s&7  (source pre-swizzled).
    int goff[4];        // per-lane global float offset (chunk-invariant part)
    const int ldsbase = dg * 1024;  // float offset of this wave's region
#pragma unroll
    for (int k = 0; k < 4; ++k) {
        const int s   = dg * 256 + k * 64 + lt;
        const int ls  = s >> 4;
        const int cs  = (s >> 3) & 1;
        const int dsl = s & 7;
        goff[k] = ls * (kC * kC) + cs * kC + ((dsl ^ (ls & 7)) << 2);
    }

    auto stage = [&](float* buf, int cb) {
#pragma unroll
        for (int k = 0; k < 4; ++k)
            async_ld16(wb + cb * (kCC * kC) + goff[k], buf + ldsbase + k * 256);
    };

    float xrA[kCC][kNB], xrB[kCC][kNB];
    auto xload = [&](float (&xr)[kCC][kNB], int cb) {
#pragma unroll
        for (int c = 0; c < kCC; ++c)
#pragma unroll
            for (int i = 0; i < kNB; ++i)
                xr[c][i] = xp[(size_t)i * (kC * kL) +
                              (size_t)(cb * kCC + c) * kL];
    };

    float acc[kNB][kND];
#pragma unroll
    for (int i = 0; i < kNB; ++i)
#pragma unroll
        for (int j = 0; j < kND; ++j) acc[i][j] = 0.0f;

    auto compute = [&](const float* buf, const float (&xr)[kCC][kNB]) {
#pragma unroll
        for (int c = 0; c < kCC; ++c) {
            // W[lt, c, d0..d0+7]: two swizzled 16B slots of row lt
            const int sl0 = lt * 16 + c * 8 + ((2 * dg) ^ (lt & 7));
            const int sl1 = lt * 16 + c * 8 + ((2 * dg + 1) ^ (lt & 7));
            const float4 w0 = *reinterpret_cast<const float4*>(buf + sl0 * 4);
            const float4 w1 = *reinterpret_cast<const float4*>(buf + sl1 * 4);
#pragma unroll
            for (int i = 0; i < kNB; ++i) {
                const float xv = xr[c][i];
                acc[i][0] += xv * w0.x;
                acc[i][1] += xv * w0.y;
                acc[i][2] += xv * w0.z;
                acc[i][3] += xv * w0.w;
                acc[i][4] += xv * w1.x;
                acc[i][5] += xv * w1.y;
                acc[i][6] += xv * w1.z;
                acc[i][7] += xv * w1.w;
            }
        }
    };

    // Prologue: chunk 0 in flight, x(0) in regs.
    stage(ldsA, 0);
    xload(xrA, 0);
    __syncthreads();  // drains the DMA, publishes ldsA

    // Steady state, unroll-2 so buffers/x-regs are statically named.
#pragma unroll 1
    for (int t = 0; t < kChunks / 2; ++t) {
        const int cbE = 2 * t;
        // even chunk: compute A, stage/prefetch odd chunk into B
        stage(ldsB, cbE + 1);
        xload(xrB, cbE + 1);
        compute(ldsA, xrA);
        __syncthreads();
        // odd chunk: compute B, stage/prefetch next even chunk into A
        if (t < kChunks / 2 - 1) {
            stage(ldsA, cbE + 2);
            xload(xrA, cbE + 2);
        }
        compute(ldsB, xrB);
        __syncthreads();
    }

    // Epilogue: bias + coalesced store.
    const float4 b0v = *reinterpret_cast<const float4*>(bias + (size_t)l * kC + d0);
    const float4 b1v = *reinterpret_cast<const float4*>(bias + (size_t)l * kC + d0 + 4);
    const float bv[kND] = {b0v.x, b0v.y, b0v.z, b0v.w, b1v.x, b1v.y, b1v.z, b1v.w};

#pragma unroll
    for (int i = 0; i < kNB; ++i) {
        float* op = out + (size_t)(b0 + i) * (kC * kL) + l;
#pragma unroll
        for (int j = 0; j < kND; ++j)
            op[(size_t)(d0 + j) * kL] = acc[i][j] + bv[j];  // coalesced over l
    }
}

}  // namespace

extern "C" void kernel_launch(void* const* d_in, const int* in_sizes, int n_in,
                              void* d_out, int out_size, void* d_ws, size_t ws_size,
                              hipStream_t stream) {
    // inputs: 0=x (B,C,H,W) fp32, 1=px (unused), 2=weight (L*C, C) fp32,
    //         3=bias (L*C) fp32
    const float* x    = (const float*)d_in[0];
    const float* wgt  = (const float*)d_in[2];
    const float* bias = (const float*)d_in[3];
    float* out = (float*)d_out;

    dim3 grid(kL / 64, 128 / kNB);  // 64 x 32 = 2048 blocks
    dim3 block(256);
    hipLaunchKernelGGL(dyna_dec, grid, block, 0, stream, x, wgt, bias, out);
}